// Round 8
// baseline (155.607 us; speedup 1.0000x reference)
//
#include <hip/hip_runtime.h>

// Problem constants
#define Jd   128   // feature dim
#define Cn   512   // num classes
#define TLn  16    // label seq length
#define Bn   32    // batch

// ---------------------------------------------------------------------------
// Reduction (x, lens dead; batch-uniform trajectory):
//   LT [tau][k][c] = L[c,tau,k]          l2T[tau][c] = ||L[c,tau,:]||^2
//   PLT[tau][j][c] = sum_k W[k][j]*L[c,tau,k]          ( = (L@W)^T )
//   S0[c]          = ||sos@W - L[c,0,:]||^2
//   DOT[s][tau][c] = l2T[tau][c] - 2*sum_j PLT[tau][j][s]*LT[tau][j][c]
//   s_0 = argmin S0;  s_t = argmin_c sum_{tau<t} DOT[s_{t-1}][tau][c]
//   out = [ broadcast_B(s_16) | broadcast_B(PLT[:, :, s_15]) ]
// Round-7 lesson: all kernels < 42us; remaining cost = 5 dispatches of work +
// gaps + harness 268MB ws-poison fill (~43us, fixed). This round: 5 -> 3
// dispatches (k_tr+k_plt fused via LDS; k_seq+k_out fused with ILP'd writes),
// k_dot microtile 8s x 4c (3 loads / 32 FMA; VALU floor 6.8us).
// ---------------------------------------------------------------------------

__device__ __forceinline__ unsigned int f2ord(float f) {
    unsigned int u = __float_as_uint(f);
    return (u & 0x80000000u) ? ~u : (u | 0x80000000u);   // monotone total order
}
__device__ __forceinline__ unsigned long long packkey(float v, int c) {
    return ((unsigned long long)f2ord(v) << 32) | (unsigned int)c;
}

// grid = 256 x 256: bid -> tau = bid&15, c0 = (bid>>4)*32.
// Phase A: stage 32 L-rows -> LDS (coalesced), emit LT + l2T.
// Phase B: PLT for this (tau, 32-c) tile from LDS Ls x LDS-staged W strips.
__global__ void k_prep2(const float* __restrict__ L, const float* __restrict__ W,
                        float* __restrict__ LT, float* __restrict__ l2T,
                        float* __restrict__ PLT) {
    __shared__ float Ls[32][132];                // 16.9 KB (+4 pad, 16B-aligned rows)
    __shared__ float Ws[32][128];                // 16 KB k-strip of W
    int tid = threadIdx.x, bid = blockIdx.x;
    int tau = bid & 15, c0 = (bid >> 4) * 32;

    // --- Phase A ---
    int r = tid >> 3, o = tid & 7;               // row 0..31, octant
    const float4* src = (const float4*)(L + ((size_t)(c0 + r) * TLn + tau) * Jd);
    float l2p = 0.f;
    #pragma unroll
    for (int i = 0; i < 4; ++i) {
        float4 v = src[o * 4 + i];
        *(float4*)&Ls[r][(o * 4 + i) * 4] = v;
        l2p += v.x * v.x + v.y * v.y + v.z * v.z + v.w * v.w;
    }
    l2p += __shfl_xor(l2p, 1, 64);
    l2p += __shfl_xor(l2p, 2, 64);
    l2p += __shfl_xor(l2p, 4, 64);
    if (o == 0) l2T[tau * Cn + c0 + r] = l2p;
    __syncthreads();
    int cc = tid & 31, jg = tid >> 5;
    #pragma unroll
    for (int j = jg; j < Jd; j += 8)             // 128B-contiguous chunks
        LT[((size_t)tau * Jd + j) * Cn + c0 + cc] = Ls[cc][j];

    // --- Phase B: PLT[tau][j][c0+ch] = sum_k Ls[ch][k] * W[k][j] ---
    int ch = tid & 31, jh = tid >> 5;            // c lane, 8 j-groups
    float acc[4][4] = {};                        // [j-strip it][j-quad u]
    for (int kb = 0; kb < 4; ++kb) {
        __syncthreads();                         // protect Ws reuse
        int kk = tid >> 3, oo = tid & 7;
        const float4* wsrc = (const float4*)(W + (size_t)(kb * 32 + kk) * Jd);
        #pragma unroll
        for (int i = 0; i < 4; ++i)
            *(float4*)&Ws[kk][(oo * 4 + i) * 4] = wsrc[oo * 4 + i];
        __syncthreads();
        #pragma unroll 8
        for (int k = 0; k < 32; ++k) {
            float lv = Ls[ch][kb * 32 + k];      // 4-way conflict (pad 132) - ok
            #pragma unroll
            for (int it = 0; it < 4; ++it) {
                float4 wv = *(const float4*)&Ws[k][it * 32 + jh * 4]; // broadcast
                acc[it][0] = fmaf(lv, wv.x, acc[it][0]);
                acc[it][1] = fmaf(lv, wv.y, acc[it][1]);
                acc[it][2] = fmaf(lv, wv.z, acc[it][2]);
                acc[it][3] = fmaf(lv, wv.w, acc[it][3]);
            }
        }
    }
    #pragma unroll
    for (int it = 0; it < 4; ++it)
        #pragma unroll
        for (int u = 0; u < 4; ++u) {            // 128B-contiguous chunks
            int j = it * 32 + jh * 4 + u;
            PLT[((size_t)tau * Jd + j) * Cn + c0 + ch] = acc[it][u];
        }
}

// grid = 513 x 256. bid<512: tau = bid&15, st = (bid>>4)&7 (64 s), cq = bid>>7
// (128 c). Microtile 8s x 4c: 3 loads / 32 FMA. bid==512: S0.
__global__ void k_dot(const float* __restrict__ LT, const float* __restrict__ PLT,
                      const float* __restrict__ l2T,
                      const float* __restrict__ sos, const float* __restrict__ W,
                      float* __restrict__ DOT, float* __restrict__ S0) {
    int tid = threadIdx.x, bid = blockIdx.x;

    if (bid == 512) {                            // ---- S0 path ----
        __shared__ float pred0[Jd];
        if (tid < Jd) {
            float a = 0.f;
            for (int k = 0; k < Jd; ++k) a = fmaf(sos[k], W[k * Jd + tid], a);
            pred0[tid] = a;
        }
        __syncthreads();
        float a0 = 0.f, a1 = 0.f;
        for (int jj = 0; jj < Jd; ++jj) {
            float p = pred0[jj];
            float d0 = p - LT[(size_t)jj * Cn + tid];        // tau = 0 plane
            float d1 = p - LT[(size_t)jj * Cn + tid + 256];
            a0 = fmaf(d0, d0, a0);
            a1 = fmaf(d1, d1, a1);
        }
        S0[tid] = a0;  S0[tid + 256] = a1;
        return;
    }

    int tau = bid & 15, st = (bid >> 4) & 7, cq = bid >> 7;
    int cg = tid & 31, sh = tid >> 5;
    int c = cq * 128 + cg * 4, s = st * 64 + sh * 8;
    const float* Bp = LT  + (size_t)tau * Jd * Cn + c;
    const float* Ap = PLT + (size_t)tau * Jd * Cn + s;
    float acc[8][4] = {};
    #pragma unroll 4
    for (int jj = 0; jj < Jd; ++jj) {
        float4 b  = *(const float4*)(Bp + (size_t)jj * Cn);  // coalesced
        float4 a0 = *(const float4*)(Ap + (size_t)jj * Cn);  // wave-broadcast
        float4 a1 = *(const float4*)(Ap + (size_t)jj * Cn + 4);
        float av[8] = {a0.x, a0.y, a0.z, a0.w, a1.x, a1.y, a1.z, a1.w};
        #pragma unroll
        for (int i = 0; i < 8; ++i) {
            acc[i][0] = fmaf(av[i], b.x, acc[i][0]);
            acc[i][1] = fmaf(av[i], b.y, acc[i][1]);
            acc[i][2] = fmaf(av[i], b.z, acc[i][2]);
            acc[i][3] = fmaf(av[i], b.w, acc[i][3]);
        }
    }
    float4 l2v = *(const float4*)(l2T + tau * Cn + c);
    #pragma unroll
    for (int i = 0; i < 8; ++i) {
        float4 v = {l2v.x - 2.f * acc[i][0], l2v.y - 2.f * acc[i][1],
                    l2v.z - 2.f * acc[i][2], l2v.w - 2.f * acc[i][3]};
        *(float4*)(DOT + ((size_t)(s + i) * TLn + tau) * Cn + c) = v;  // coalesced
    }
}

// 1 block x 256: 17-step argmin chain (32 loads in flight per step, mask-FMA)
// + fused output write (8 gather loads in flight, then coalesced 256B stores).
__global__ void k_fin(const float* __restrict__ S0, const float* __restrict__ DOT,
                      const float* __restrict__ PLT, float* __restrict__ out) {
    __shared__ unsigned long long red[4];
    __shared__ int sCur;
    __shared__ int keys[TLn + 1];
    int tid = threadIdx.x, w = tid >> 6, lane = tid & 63;

    for (int t = 0; t <= TLn; ++t) {
        float sum0, sum1;
        if (t == 0) {
            sum0 = S0[tid];  sum1 = S0[tid + 256];
        } else {
            const float* base = DOT + (size_t)sCur * TLn * Cn;
            float v0[TLn], v1[TLn];
            #pragma unroll
            for (int tau = 0; tau < TLn; ++tau) {            // 32 independent loads
                v0[tau] = base[(size_t)tau * Cn + tid];
                v1[tau] = base[(size_t)tau * Cn + tid + 256];
            }
            sum0 = sum1 = 0.f;
            #pragma unroll
            for (int tau = 0; tau < TLn; ++tau) {
                float m = (tau < t) ? 1.f : 0.f;
                sum0 = fmaf(v0[tau], m, sum0);
                sum1 = fmaf(v1[tau], m, sum1);
            }
        }
        unsigned long long m0 = packkey(sum0, tid);
        unsigned long long m1 = packkey(sum1, tid + 256);
        unsigned long long m = (m1 < m0) ? m1 : m0;
        for (int o = 32; o; o >>= 1) {
            unsigned long long o2 = __shfl_down(m, o, 64);
            if (o2 < m) m = o2;
        }
        if (lane == 0) red[w] = m;
        __syncthreads();
        if (tid == 0) {
            unsigned long long b = red[0];
            #pragma unroll
            for (int i = 1; i < 4; ++i) if (red[i] < b) b = red[i];
            int sv = (int)(b & 0xFFFFFFFFull);
            sCur = sv;  keys[t] = sv;
        }
        __syncthreads();
    }

    // ---- output: [sofar(32) | pls(B,TL,J)] ----
    int s16 = keys[TLn], s15 = keys[TLn - 1];
    float v[8];
    #pragma unroll
    for (int q = 0; q < 8; ++q)                  // 8 independent gathers in flight
        v[q] = PLT[(size_t)(q * 256 + tid) * Cn + s15];
    if (tid < Bn) out[tid] = (float)s16;
    #pragma unroll
    for (int q = 0; q < 8; ++q)
        for (int b = 0; b < Bn; ++b)             // 256B contiguous per store inst
            out[Bn + (size_t)b * (TLn * Jd) + q * 256 + tid] = v[q];
}

extern "C" void kernel_launch(void* const* d_in, const int* in_sizes, int n_in,
                              void* d_out, int out_size, void* d_ws, size_t ws_size,
                              hipStream_t stream) {
    // inputs: 0:x (dead, 32MB), 1:lens (dead), 2:sos, 3:label_seqs, 4:W  (all f32)
    const float* sos = (const float*)d_in[2];
    const float* L   = (const float*)d_in[3];
    const float* W   = (const float*)d_in[4];
    float* out = (float*)d_out;

    // ws: S0(2KB)@0 | l2T(32KB)@4K | PLT(4MB)@64K | LT(4MB) | DOT(16.8MB)
    const size_t l2Off  = 4096;
    const size_t pltOff = 65536;
    const size_t ltOff  = pltOff + (size_t)TLn * Jd * Cn * sizeof(float);
    const size_t dotOff = ltOff  + (size_t)TLn * Jd * Cn * sizeof(float);
    const size_t need   = dotOff + (size_t)Cn * TLn * Cn * sizeof(float);  // ~25 MB
    char* base = (ws_size >= need) ? (char*)d_ws : (char*)d_in[0];  // x dead, 32 MB
    float* S0   = (float*)base;
    float* l2T  = (float*)(base + l2Off);
    float* PLT  = (float*)(base + pltOff);
    float* LT   = (float*)(base + ltOff);
    float* DOT  = (float*)(base + dotOff);

    hipLaunchKernelGGL(k_prep2, dim3(256), dim3(256), 0, stream, L, W, LT, l2T, PLT);
    hipLaunchKernelGGL(k_dot,   dim3(513), dim3(256), 0, stream,
                       LT, PLT, l2T, sos, W, DOT, S0);
    hipLaunchKernelGGL(k_fin,   dim3(1),   dim3(256), 0, stream, S0, DOT, PLT, out);
}